// Round 14
// baseline (489.190 us; speedup 1.0000x reference)
//
#include <hip/hip_runtime.h>
#include <hip/hip_fp16.h>
#include <stdint.h>

// GNN: 2x SAGEConv(mean)+ReLU + mean-pool + linear, algebraically refactored:
//  te = emb@W1l^T (fp16 gather table), trb = emb@W1r^T + b1 (fp32)
//  k_gather1: h1 = relu(mean(te[x[src]]) + trb[x[n]])          (fp16)
//  k_gemm   : g1 = h1@W2l^T (fp16); s1 = h1@W2r^T + b2 (fp32)  [MFMA 16x16x32]
//  k_conv2  : h2 = relu(mean(g1[src]) + s1[n]); o[n] = h2@Wout^T
//  k_pool   : out[g] = mean(o) + bout
// idx[pos] = (x[src]<<18) | src, stored bucket-SPARSE (cap-strided regions);
// per-node obeg/oend point into it, so no dense compaction scan is needed.
// Conv/gather kernels: 2 nodes per wave -> up to 16 row-gathers in flight
// (R13 showed 1-node waves cap at ~4 for deg~32; latency-MLP bound).

#define NPB 4
#define NBUCK 256
#define TILE 4096
#define EPT 16
#define MAXN 1024

typedef __attribute__((ext_vector_type(8))) _Float16 half8;
typedef __attribute__((ext_vector_type(4))) float f32x4;

__device__ __forceinline__ int bucket_of(int dstv, int n_nodes) {
  return (int)(((unsigned)dstv * 256u) / (unsigned)n_nodes);
}

// masked accumulate
__device__ __forceinline__ void acc8h(float* a, uint4 u, float m) {
  const __half2* hp = (const __half2*)&u;
#pragma unroll
  for (int q = 0; q < 4; ++q) {
    float2 f = __half22float2(hp[q]);
    a[2 * q]     = fmaf(m, f.x, a[2 * q]);
    a[2 * q + 1] = fmaf(m, f.y, a[2 * q + 1]);
  }
}

// unmasked accumulate
__device__ __forceinline__ void add8(float* a, uint4 u) {
  const __half2* hp = (const __half2*)&u;
#pragma unroll
  for (int q = 0; q < 4; ++q) {
    float2 f = __half22float2(hp[q]);
    a[2 * q]     += f.x;
    a[2 * q + 1] += f.y;
  }
}

// LDS-tile multisplit with 4-way sub-histograms (per-wave)
__global__ void k_part(const int* __restrict__ src, const int* __restrict__ dst,
                       int* __restrict__ gcur, unsigned* __restrict__ pairs,
                       int n_edges, int n_nodes, int chunk) {
  __shared__ int hist[NBUCK * 4];
  __shared__ int base[NBUCK * 4];
  int t = threadIdx.x;
  int g = t >> 6;
  int beg = blockIdx.x * chunk;
  int end = min(beg + chunk, n_edges);
  for (int tbeg = beg; tbeg < end; tbeg += TILE) {
    int cnt = min(TILE, end - tbeg);
    hist[t] = 0; hist[t + 256] = 0; hist[t + 512] = 0; hist[t + 768] = 0;
    __syncthreads();
    unsigned pk[EPT];
    int r[EPT], bk[EPT];
    bool v[EPT];
#pragma unroll
    for (int k = 0; k < EPT; ++k) {
      int li = k * 256 + t;
      v[k] = li < cnt;
      if (v[k]) {
        int i = tbeg + li;
        int s = src[i];
        int d = dst[i];
        bk[k] = bucket_of(d, n_nodes);
        unsigned nb0 = ((unsigned)bk[k] * (unsigned)n_nodes + 255u) >> 8;
        pk[k] = (((unsigned)d - nb0) << 18) | (unsigned)s;
        r[k] = atomicAdd(&hist[bk[k] * 4 + g], 1);
      }
    }
    __syncthreads();
    int h0 = hist[t * 4 + 0], h1 = hist[t * 4 + 1];
    int h2 = hist[t * 4 + 2], h3 = hist[t * 4 + 3];
    int tot = h0 + h1 + h2 + h3;
    int b0 = (tot > 0) ? atomicAdd(&gcur[t], tot) : 0;
    base[t * 4 + 0] = b0;
    base[t * 4 + 1] = b0 + h0;
    base[t * 4 + 2] = b0 + h0 + h1;
    base[t * 4 + 3] = b0 + h0 + h1 + h2;
    __syncthreads();
#pragma unroll
    for (int k = 0; k < EPT; ++k)
      if (v[k]) pairs[base[bk[k] * 4 + g] + r[k]] = pk[k];
    __syncthreads();
  }
}

// one block per bucket: LDS node-hist -> scan -> obeg/oend (into SPARSE idx);
// scatter packed (x[src]<<18|src) into the bucket's own region.
__global__ void k_bucket(const unsigned* __restrict__ pairs, const int* __restrict__ gcur,
                         const int* __restrict__ x, int* __restrict__ obeg,
                         int* __restrict__ oend, unsigned* __restrict__ idx,
                         int n_nodes, int cap) {
  __shared__ int lcnt[MAXN];
  __shared__ int lcur[MAXN];
  __shared__ int stmp[256];
  int b = blockIdx.x, t = threadIdx.x;
  int nb0 = (int)((((unsigned)b * (unsigned)n_nodes) + 255u) >> 8);
  int nb1 = (int)((((unsigned)(b + 1) * (unsigned)n_nodes) + 255u) >> 8);
  if (nb1 > n_nodes) nb1 = n_nodes;
  int nn = nb1 - nb0;
  int rbeg = b * cap;
  int rend = gcur[b];
  for (int i = t; i < nn; i += 256) lcnt[i] = 0;
  __syncthreads();
  for (int i = rbeg + t; i < rend; i += 256)
    atomicAdd(&lcnt[pairs[i] >> 18], 1);
  __syncthreads();
  int i0 = t * 4;
  int v0 = (i0 + 0 < nn) ? lcnt[i0 + 0] : 0;
  int v1 = (i0 + 1 < nn) ? lcnt[i0 + 1] : 0;
  int v2 = (i0 + 2 < nn) ? lcnt[i0 + 2] : 0;
  int v3 = (i0 + 3 < nn) ? lcnt[i0 + 3] : 0;
  stmp[t] = v0 + v1 + v2 + v3;
  __syncthreads();
  for (int off = 1; off < 256; off <<= 1) {
    int add = (t >= off) ? stmp[t - off] : 0;
    __syncthreads();
    stmp[t] += add;
    __syncthreads();
  }
  int run = rbeg + ((t == 0) ? 0 : stmp[t - 1]);
  if (i0 + 0 < nn) { lcur[i0 + 0] = run; obeg[nb0 + i0 + 0] = run; oend[nb0 + i0 + 0] = run + v0; run += v0; }
  if (i0 + 1 < nn) { lcur[i0 + 1] = run; obeg[nb0 + i0 + 1] = run; oend[nb0 + i0 + 1] = run + v1; run += v1; }
  if (i0 + 2 < nn) { lcur[i0 + 2] = run; obeg[nb0 + i0 + 2] = run; oend[nb0 + i0 + 2] = run + v2; run += v2; }
  if (i0 + 3 < nn) { lcur[i0 + 3] = run; obeg[nb0 + i0 + 3] = run; oend[nb0 + i0 + 3] = run + v3; run += v3; }
  __syncthreads();
  for (int i = rbeg + t; i < rend; i += 256) {
    unsigned e = pairs[i];
    int s = (int)(e & 0x3FFFFu);
    int pos = atomicAdd(&lcur[e >> 18], 1);
    idx[pos] = ((unsigned)x[s] << 18) | (unsigned)s;
  }
}

__global__ void k_transpose4(const float* __restrict__ a0, const float* __restrict__ a1,
                             const float* __restrict__ a2, const float* __restrict__ a3,
                             float* __restrict__ wt) {
  const float* s = (blockIdx.x == 0) ? a0 : (blockIdx.x == 1) ? a1 : (blockIdx.x == 2) ? a2 : a3;
  float* d = wt + blockIdx.x * 4096;
  for (int i = threadIdx.x; i < 4096; i += blockDim.x) {
    int r = i >> 6, c = i & 63;
    d[c * 64 + r] = s[i];
  }
}

// pack W2l,W2r into MFMA B-fragment order (same k-map as A: k=(l>>4)*8+j)
// + folds cursor init (block 0).
__global__ void k_packB(const float* __restrict__ W2l, const float* __restrict__ W2r,
                        __half* __restrict__ pB, int* __restrict__ gcur, int cap) {
  if (blockIdx.x == 0) gcur[threadIdx.x] = threadIdx.x * cap;
  int i = blockIdx.x * 256 + threadIdx.x;
  if (i >= 8192) return;
  int j = i & 7, l = (i >> 3) & 63, kt = (i >> 9) & 1, nt = (i >> 10) & 3, mat = i >> 12;
  int k = kt * 32 + (l >> 4) * 8 + j;
  int n = nt * 16 + (l & 15);
  const float* W = mat ? W2r : W2l;
  pB[i] = __float2half(W[n * 64 + k]);
}

__global__ void k_prep(const float* __restrict__ emb, const float* __restrict__ w1lT,
                       const float* __restrict__ w1rT, const float* __restrict__ b1,
                       __half* __restrict__ te, float* __restrict__ trb, int vocab) {
  __shared__ float se[NPB][64];
  int wid = threadIdx.x >> 6, lane = threadIdx.x & 63;
  int v = blockIdx.x * NPB + wid;
  if (v >= vocab) return;
  se[wid][lane] = emb[(size_t)v * 64 + lane];
  __syncwarp();
  float aL = 0.f, aR = b1[lane];
#pragma unroll 8
  for (int f = 0; f < 64; ++f) {
    float ev = se[wid][f];
    aL = fmaf(ev, w1lT[f * 64 + lane], aL);
    aR = fmaf(ev, w1rT[f * 64 + lane], aR);
  }
  te[(size_t)v * 64 + lane] = __float2half(aL);
  trb[(size_t)v * 64 + lane] = aR;
}

// load 1 row-group J for node-stream (EIX,NIT,NG) from TBL with index op OP
#define LDG(U, J, EIX, NIT, NG, TBL, OP) \
  if (J < NG) { int vv = (int)(__shfl(EIX, min(J * 8 + r8, NIT - 1)) OP); \
    U = *(const uint4*)(TBL + ((size_t)vv << 6) + s8); }
#define ACG(U, J, NF, NG, NIT, ACC) \
  if (J < NF) add8(ACC, U); \
  else if (J < NG) acc8h(ACC, U, (J * 8 + r8 < NIT) ? 1.f : 0.f);

// gather1: 2 nodes/wave; gather te rows; h1 = relu(mean + trb[x]) (fp16)
__global__ __launch_bounds__(64, 4) void
k_gather1(const unsigned* __restrict__ idx, const int* __restrict__ obeg,
          const int* __restrict__ oend, const __half* __restrict__ te,
          const float* __restrict__ trb, const int* __restrict__ x,
          __half* __restrict__ h1, int n_nodes) {
  int lane = threadIdx.x;
  int r8 = lane >> 3, s8 = (lane & 7) << 3;
  int n0 = blockIdx.x * 2;
  int n1 = n0 + 1;
  if (n0 >= n_nodes) return;
  bool has1 = n1 < n_nodes;
  int xv0 = x[n0];
  int xv1 = has1 ? x[n1] : 0;
  int b0 = obeg[n0], e0 = oend[n0];
  int b1 = has1 ? obeg[n1] : 0, e1 = has1 ? oend[n1] : 0;
  float a0[8], a1[8];
#pragma unroll
  for (int q = 0; q < 8; ++q) { a0[q] = 0.f; a1[q] = 0.f; }
  int c0 = b0, c1 = b1;
  while (c0 < e0 || c1 < e1) {
    int nit0 = (c0 < e0) ? min(e0 - c0, 64) : 0;
    int nit1 = (c1 < e1) ? min(e1 - c1, 64) : 0;
    unsigned ei0 = 0, ei1 = 0;
    if (nit0) ei0 = idx[c0 + min(lane, nit0 - 1)];
    if (nit1) ei1 = idx[c1 + min(lane, nit1 - 1)];
    int ng0 = (nit0 + 7) >> 3, nf0 = nit0 >> 3;
    int ng1 = (nit1 + 7) >> 3, nf1 = nit1 >> 3;
    uint4 uA0, uA1, uA2, uA3, uA4, uA5, uA6, uA7;
    uint4 uB0, uB1, uB2, uB3, uB4, uB5, uB6, uB7;
    LDG(uA0, 0, ei0, nit0, ng0, te, >> 18) LDG(uA1, 1, ei0, nit0, ng0, te, >> 18)
    LDG(uA2, 2, ei0, nit0, ng0, te, >> 18) LDG(uA3, 3, ei0, nit0, ng0, te, >> 18)
    LDG(uA4, 4, ei0, nit0, ng0, te, >> 18) LDG(uA5, 5, ei0, nit0, ng0, te, >> 18)
    LDG(uA6, 6, ei0, nit0, ng0, te, >> 18) LDG(uA7, 7, ei0, nit0, ng0, te, >> 18)
    LDG(uB0, 0, ei1, nit1, ng1, te, >> 18) LDG(uB1, 1, ei1, nit1, ng1, te, >> 18)
    LDG(uB2, 2, ei1, nit1, ng1, te, >> 18) LDG(uB3, 3, ei1, nit1, ng1, te, >> 18)
    LDG(uB4, 4, ei1, nit1, ng1, te, >> 18) LDG(uB5, 5, ei1, nit1, ng1, te, >> 18)
    LDG(uB6, 6, ei1, nit1, ng1, te, >> 18) LDG(uB7, 7, ei1, nit1, ng1, te, >> 18)
    ACG(uA0, 0, nf0, ng0, nit0, a0) ACG(uA1, 1, nf0, ng0, nit0, a0)
    ACG(uA2, 2, nf0, ng0, nit0, a0) ACG(uA3, 3, nf0, ng0, nit0, a0)
    ACG(uA4, 4, nf0, ng0, nit0, a0) ACG(uA5, 5, nf0, ng0, nit0, a0)
    ACG(uA6, 6, nf0, ng0, nit0, a0) ACG(uA7, 7, nf0, ng0, nit0, a0)
    ACG(uB0, 0, nf1, ng1, nit1, a1) ACG(uB1, 1, nf1, ng1, nit1, a1)
    ACG(uB2, 2, nf1, ng1, nit1, a1) ACG(uB3, 3, nf1, ng1, nit1, a1)
    ACG(uB4, 4, nf1, ng1, nit1, a1) ACG(uB5, 5, nf1, ng1, nit1, a1)
    ACG(uB6, 6, nf1, ng1, nit1, a1) ACG(uB7, 7, nf1, ng1, nit1, a1)
    c0 += 64; c1 += 64;
  }
  // issue trb rows before the reduces so their latency hides under them
  float4 t00, t01, t10, t11;
  if (lane < 8) {
    const float* tp0 = trb + ((size_t)xv0 << 6) + s8;
    t00 = *(const float4*)tp0;
    t01 = *(const float4*)(tp0 + 4);
    const float* tp1 = trb + ((size_t)xv1 << 6) + s8;
    t10 = *(const float4*)tp1;
    t11 = *(const float4*)(tp1 + 4);
  }
#pragma unroll
  for (int q = 0; q < 8; ++q) {
    a0[q] += __shfl_xor(a0[q], 8);  a0[q] += __shfl_xor(a0[q], 16); a0[q] += __shfl_xor(a0[q], 32);
    a1[q] += __shfl_xor(a1[q], 8);  a1[q] += __shfl_xor(a1[q], 16); a1[q] += __shfl_xor(a1[q], 32);
  }
  int d0 = e0 - b0, d1 = e1 - b1;
  float inv0 = (d0 > 0) ? 1.f / (float)d0 : 0.f;
  float inv1 = (d1 > 0) ? 1.f / (float)d1 : 0.f;
  if (lane < 8) {
    __half hh[8];
    hh[0] = __float2half(fmaxf(fmaf(a0[0], inv0, t00.x), 0.f));
    hh[1] = __float2half(fmaxf(fmaf(a0[1], inv0, t00.y), 0.f));
    hh[2] = __float2half(fmaxf(fmaf(a0[2], inv0, t00.z), 0.f));
    hh[3] = __float2half(fmaxf(fmaf(a0[3], inv0, t00.w), 0.f));
    hh[4] = __float2half(fmaxf(fmaf(a0[4], inv0, t01.x), 0.f));
    hh[5] = __float2half(fmaxf(fmaf(a0[5], inv0, t01.y), 0.f));
    hh[6] = __float2half(fmaxf(fmaf(a0[6], inv0, t01.z), 0.f));
    hh[7] = __float2half(fmaxf(fmaf(a0[7], inv0, t01.w), 0.f));
    *(uint4*)(h1 + ((size_t)n0 << 6) + s8) = *(uint4*)hh;
    if (has1) {
      hh[0] = __float2half(fmaxf(fmaf(a1[0], inv1, t10.x), 0.f));
      hh[1] = __float2half(fmaxf(fmaf(a1[1], inv1, t10.y), 0.f));
      hh[2] = __float2half(fmaxf(fmaf(a1[2], inv1, t10.z), 0.f));
      hh[3] = __float2half(fmaxf(fmaf(a1[3], inv1, t10.w), 0.f));
      hh[4] = __float2half(fmaxf(fmaf(a1[4], inv1, t11.x), 0.f));
      hh[5] = __float2half(fmaxf(fmaf(a1[5], inv1, t11.y), 0.f));
      hh[6] = __float2half(fmaxf(fmaf(a1[6], inv1, t11.z), 0.f));
      hh[7] = __float2half(fmaxf(fmaf(a1[7], inv1, t11.w), 0.f));
      *(uint4*)(h1 + ((size_t)n1 << 6) + s8) = *(uint4*)hh;
    }
  }
}

// MFMA mini-GEMM: [16 nodes x 64] @ {W2l^T, W2r^T} -> g1 (fp16), s1 (fp32, +b2)
__global__ __launch_bounds__(64) void
k_gemm(const __half* __restrict__ h1, const __half* __restrict__ pB,
       const float* __restrict__ b2, __half* __restrict__ g1,
       float* __restrict__ s1, int n_nodes) {
  int lane = threadIdx.x;
  int nbase = blockIdx.x * 16;
  int row = lane & 15, grp = lane >> 4;
  const half8 a0 = *(const half8*)(h1 + ((size_t)(nbase + row) << 6) + grp * 8);
  const half8 a1 = *(const half8*)(h1 + ((size_t)(nbase + row) << 6) + 32 + grp * 8);
#pragma unroll
  for (int t = 0; t < 8; ++t) {
    const half8 b0 = *(const half8*)(pB + (t * 2 + 0) * 512 + lane * 8);
    const half8 b1 = *(const half8*)(pB + (t * 2 + 1) * 512 + lane * 8);
    f32x4 acc = {0.f, 0.f, 0.f, 0.f};
    acc = __builtin_amdgcn_mfma_f32_16x16x32_f16(a0, b0, acc, 0, 0, 0);
    acc = __builtin_amdgcn_mfma_f32_16x16x32_f16(a1, b1, acc, 0, 0, 0);
    int out = (t & 3) * 16 + (lane & 15);
    if (t < 4) {
#pragma unroll
      for (int r = 0; r < 4; ++r) {
        int node = nbase + grp * 4 + r;
        if (node < n_nodes) g1[((size_t)node << 6) + out] = __float2half(acc[r]);
      }
    } else {
      float bias = b2[out];
#pragma unroll
      for (int r = 0; r < 4; ++r) {
        int node = nbase + grp * 4 + r;
        if (node < n_nodes) s1[((size_t)node << 6) + out] = acc[r] + bias;
      }
    }
  }
}

// conv2: 2 nodes/wave; gather g1 + mean + s1 + relu -> o = h2@Wout^T
__global__ __launch_bounds__(64, 4) void
k_conv2(const unsigned* __restrict__ idx, const int* __restrict__ obeg,
        const int* __restrict__ oend, const __half* __restrict__ g1,
        const float* __restrict__ s1, const float* __restrict__ wout,
        float* __restrict__ o, int n_nodes) {
  __shared__ float sm[2][64];
  int lane = threadIdx.x;
  int r8 = lane >> 3, s8 = (lane & 7) << 3;
  int n0 = blockIdx.x * 2;
  int n1 = n0 + 1;
  if (n0 >= n_nodes) return;
  bool has1 = n1 < n_nodes;
  float s1v0 = s1[((size_t)n0 << 6) + lane];
  float s1v1 = has1 ? s1[((size_t)n1 << 6) + lane] : 0.f;
  float w0 = wout[lane], w1v = wout[64 + lane];
  int b0 = obeg[n0], e0 = oend[n0];
  int b1 = has1 ? obeg[n1] : 0, e1 = has1 ? oend[n1] : 0;
  float a0[8], a1[8];
#pragma unroll
  for (int q = 0; q < 8; ++q) { a0[q] = 0.f; a1[q] = 0.f; }
  int c0 = b0, c1 = b1;
  while (c0 < e0 || c1 < e1) {
    int nit0 = (c0 < e0) ? min(e0 - c0, 64) : 0;
    int nit1 = (c1 < e1) ? min(e1 - c1, 64) : 0;
    unsigned ei0 = 0, ei1 = 0;
    if (nit0) ei0 = idx[c0 + min(lane, nit0 - 1)];
    if (nit1) ei1 = idx[c1 + min(lane, nit1 - 1)];
    int ng0 = (nit0 + 7) >> 3, nf0 = nit0 >> 3;
    int ng1 = (nit1 + 7) >> 3, nf1 = nit1 >> 3;
    uint4 uA0, uA1, uA2, uA3, uA4, uA5, uA6, uA7;
    uint4 uB0, uB1, uB2, uB3, uB4, uB5, uB6, uB7;
    LDG(uA0, 0, ei0, nit0, ng0, g1, & 0x3FFFFu) LDG(uA1, 1, ei0, nit0, ng0, g1, & 0x3FFFFu)
    LDG(uA2, 2, ei0, nit0, ng0, g1, & 0x3FFFFu) LDG(uA3, 3, ei0, nit0, ng0, g1, & 0x3FFFFu)
    LDG(uA4, 4, ei0, nit0, ng0, g1, & 0x3FFFFu) LDG(uA5, 5, ei0, nit0, ng0, g1, & 0x3FFFFu)
    LDG(uA6, 6, ei0, nit0, ng0, g1, & 0x3FFFFu) LDG(uA7, 7, ei0, nit0, ng0, g1, & 0x3FFFFu)
    LDG(uB0, 0, ei1, nit1, ng1, g1, & 0x3FFFFu) LDG(uB1, 1, ei1, nit1, ng1, g1, & 0x3FFFFu)
    LDG(uB2, 2, ei1, nit1, ng1, g1, & 0x3FFFFu) LDG(uB3, 3, ei1, nit1, ng1, g1, & 0x3FFFFu)
    LDG(uB4, 4, ei1, nit1, ng1, g1, & 0x3FFFFu) LDG(uB5, 5, ei1, nit1, ng1, g1, & 0x3FFFFu)
    LDG(uB6, 6, ei1, nit1, ng1, g1, & 0x3FFFFu) LDG(uB7, 7, ei1, nit1, ng1, g1, & 0x3FFFFu)
    ACG(uA0, 0, nf0, ng0, nit0, a0) ACG(uA1, 1, nf0, ng0, nit0, a0)
    ACG(uA2, 2, nf0, ng0, nit0, a0) ACG(uA3, 3, nf0, ng0, nit0, a0)
    ACG(uA4, 4, nf0, ng0, nit0, a0) ACG(uA5, 5, nf0, ng0, nit0, a0)
    ACG(uA6, 6, nf0, ng0, nit0, a0) ACG(uA7, 7, nf0, ng0, nit0, a0)
    ACG(uB0, 0, nf1, ng1, nit1, a1) ACG(uB1, 1, nf1, ng1, nit1, a1)
    ACG(uB2, 2, nf1, ng1, nit1, a1) ACG(uB3, 3, nf1, ng1, nit1, a1)
    ACG(uB4, 4, nf1, ng1, nit1, a1) ACG(uB5, 5, nf1, ng1, nit1, a1)
    ACG(uB6, 6, nf1, ng1, nit1, a1) ACG(uB7, 7, nf1, ng1, nit1, a1)
    c0 += 64; c1 += 64;
  }
#pragma unroll
  for (int q = 0; q < 8; ++q) {
    a0[q] += __shfl_xor(a0[q], 8);  a0[q] += __shfl_xor(a0[q], 16); a0[q] += __shfl_xor(a0[q], 32);
    a1[q] += __shfl_xor(a1[q], 8);  a1[q] += __shfl_xor(a1[q], 16); a1[q] += __shfl_xor(a1[q], 32);
  }
  int d0 = e0 - b0, d1 = e1 - b1;
  float inv0 = (d0 > 0) ? 1.f / (float)d0 : 0.f;
  float inv1 = (d1 > 0) ? 1.f / (float)d1 : 0.f;
  if (lane < 8) {
#pragma unroll
    for (int q = 0; q < 8; ++q) {
      sm[0][s8 + q] = a0[q] * inv0;
      sm[1][s8 + q] = a1[q] * inv1;
    }
  }
  __syncthreads();
  float h20 = fmaxf(sm[0][lane] + s1v0, 0.f);
  float h21 = fmaxf(sm[1][lane] + s1v1, 0.f);
  float p00 = h20 * w0, p01 = h20 * w1v;
  float p10 = h21 * w0, p11 = h21 * w1v;
  for (int off = 32; off > 0; off >>= 1) {
    p00 += __shfl_down(p00, off);
    p01 += __shfl_down(p01, off);
    p10 += __shfl_down(p10, off);
    p11 += __shfl_down(p11, off);
  }
  if (lane == 0) {
    o[((size_t)n0 << 1) + 0] = p00;
    o[((size_t)n0 << 1) + 1] = p01;
    if (has1) {
      o[((size_t)n1 << 1) + 0] = p10;
      o[((size_t)n1 << 1) + 1] = p11;
    }
  }
}

__global__ void k_goffs(const int* __restrict__ batch, int* __restrict__ goffs,
                        int n_nodes, int n_graphs) {
  int i = blockIdx.x * blockDim.x + threadIdx.x;
  if (i >= n_nodes) return;
  int b = batch[i];
  int bp = (i == 0) ? -1 : batch[i - 1];
  for (int g = bp + 1; g <= b; ++g) goffs[g] = i;
  if (i == n_nodes - 1)
    for (int g = b + 1; g <= n_graphs; ++g) goffs[g] = n_nodes;
}

__global__ void k_pool(const float2* __restrict__ o, const int* __restrict__ goffs,
                       const float* __restrict__ bout, float* __restrict__ out,
                       int n_graphs) {
  int wid = threadIdx.x >> 6, lane = threadIdx.x & 63;
  int g = blockIdx.x * NPB + wid;
  if (g >= n_graphs) return;
  int beg = goffs[g], end = goffs[g + 1];
  float a0 = 0.f, a1 = 0.f;
  for (int n = beg + lane; n < end; n += 64) {
    float2 v = o[n];
    a0 += v.x;
    a1 += v.y;
  }
  for (int off = 32; off > 0; off >>= 1) {
    a0 += __shfl_down(a0, off);
    a1 += __shfl_down(a1, off);
  }
  if (lane == 0) {
    int cnt = end - beg;
    float inv = (cnt > 0) ? 1.f / (float)cnt : 0.f;
    out[g * 2 + 0] = a0 * inv + bout[0];
    out[g * 2 + 1] = a1 * inv + bout[1];
  }
}

extern "C" void kernel_launch(void* const* d_in, const int* in_sizes, int n_in,
                              void* d_out, int out_size, void* d_ws, size_t ws_size,
                              hipStream_t stream) {
  const int* x = (const int*)d_in[0];
  const int* ei = (const int*)d_in[1];
  const int* batch = (const int*)d_in[2];
  const float* emb = (const float*)d_in[3];
  const float* W1l = (const float*)d_in[4];
  const float* b1 = (const float*)d_in[5];
  const float* W1r = (const float*)d_in[6];
  const float* W2l = (const float*)d_in[7];
  const float* b2 = (const float*)d_in[8];
  const float* W2r = (const float*)d_in[9];
  const float* Wout = (const float*)d_in[10];
  const float* bout = (const float*)d_in[11];
  float* out = (float*)d_out;

  int n_nodes = in_sizes[0];
  int n_edges = in_sizes[1] / 2;
  int vocab = in_sizes[3] / 64;
  int n_graphs = out_size / 2;
  const int* src = ei;
  const int* dst = ei + n_edges;

  int cap = n_edges / NBUCK + n_edges / (NBUCK * 8) + 1024;
  int ntiles = (n_nodes + 15) / 16;

  char* p = (char*)d_ws;
  auto alloc = [&](size_t bytes) -> void* {
    void* r = (void*)p;
    p += (bytes + 255) & ~(size_t)255;
    return r;
  };
  __half* te = (__half*)alloc((size_t)vocab * 64 * 2);
  float* trb = (float*)alloc((size_t)vocab * 64 * 4);
  float* wt = (float*)alloc(2 * 4096 * 4);
  __half* pB = (__half*)alloc(8192 * 2);
  int* obeg = (int*)alloc((size_t)n_nodes * 4);
  int* oend = (int*)alloc((size_t)n_nodes * 4);
  int* goffs = (int*)alloc((size_t)(n_graphs + 1) * 4);
  int* gcur = (int*)alloc(NBUCK * 4);
  unsigned* idx = (unsigned*)alloc((size_t)NBUCK * cap * 4);  // bucket-sparse
  __half* h1 = (__half*)alloc((size_t)(ntiles * 16) * 64 * 2);
  size_t pairs_bytes = (size_t)NBUCK * cap * 4;
  size_t g1_bytes = (size_t)n_nodes * 64 * 2;
  unsigned* pairs = (unsigned*)alloc(pairs_bytes > g1_bytes ? pairs_bytes : g1_bytes);
  float* s1 = (float*)alloc((size_t)n_nodes * 64 * 4);
  float* o = (float*)alloc((size_t)n_nodes * 2 * 4);
  __half* g1 = (__half*)pairs;  // pairs dead before k_gemm writes g1

  k_packB<<<32, 256, 0, stream>>>(W2l, W2r, pB, gcur, cap);  // + cursor init
  k_transpose4<<<2, 256, 0, stream>>>(W1l, W1r, W1l, W1l, wt);
  k_prep<<<(vocab + NPB - 1) / NPB, 64 * NPB, 0, stream>>>(emb, wt, wt + 4096, b1, te, trb, vocab);

  int part_blocks = 512;
  int chunk = (n_edges + part_blocks - 1) / part_blocks;
  k_part<<<part_blocks, 256, 0, stream>>>(src, dst, gcur, pairs, n_edges, n_nodes, chunk);
  k_bucket<<<NBUCK, 256, 0, stream>>>(pairs, gcur, x, obeg, oend, idx, n_nodes, cap);

  k_goffs<<<(n_nodes + 255) / 256, 256, 0, stream>>>(batch, goffs, n_nodes, n_graphs);

  k_gather1<<<(n_nodes + 1) / 2, 64, 0, stream>>>(idx, obeg, oend, te, trb, x, h1, n_nodes);
  k_gemm<<<ntiles, 64, 0, stream>>>(h1, pB, b2, g1, s1, n_nodes);
  k_conv2<<<(n_nodes + 1) / 2, 64, 0, stream>>>(idx, obeg, oend, g1, s1, Wout, o, n_nodes);
  k_pool<<<(n_graphs + NPB - 1) / NPB, 64 * NPB, 0, stream>>>((const float2*)o, goffs, bout, out, n_graphs);
}

// Round 15
// 398.348 us; speedup vs baseline: 1.2280x; 1.2280x over previous
//
#include <hip/hip_runtime.h>
#include <hip/hip_fp16.h>
#include <stdint.h>

// GNN: 2x SAGEConv(mean)+ReLU + mean-pool + linear, algebraically refactored:
//  te = emb@W1l^T (fp16 gather table), trb = emb@W1r^T + b1 (fp32)
//  k_gather1: h1 = relu(mean(te[x[src]]) + trb[x[n]])          (fp16)
//  k_gemm   : g1 = h1@W2l^T (fp16); s1 = h1@W2r^T + b2 (fp32)  [MFMA 16x16x32]
//  k_conv2  : h2 = relu(mean(g1[src]) + s1[n]); o[n] = h2@Wout^T
//  k_pool   : out[g] = mean(o) + bout
// idx[pos] = (x[src]<<18) | src, stored bucket-SPARSE (cap-strided regions);
// per-node obeg/oend point into it (no dense compaction scan).
// Conv/gather: 1 node/wave (R14's 2-node/wave: VGPR 60, occ 43% -> REGRESSION;
// R13's 36-VGPR / 72%-occ point is the measured optimum for this gather).

#define NPB 4
#define NBUCK 256
#define TILE 4096
#define EPT 16
#define MAXN 1024

typedef __attribute__((ext_vector_type(8))) _Float16 half8;
typedef __attribute__((ext_vector_type(4))) float f32x4;

__device__ __forceinline__ int bucket_of(int dstv, int n_nodes) {
  return (int)(((unsigned)dstv * 256u) / (unsigned)n_nodes);
}

// masked accumulate
__device__ __forceinline__ void acc8h(float* a, uint4 u, float m) {
  const __half2* hp = (const __half2*)&u;
#pragma unroll
  for (int q = 0; q < 4; ++q) {
    float2 f = __half22float2(hp[q]);
    a[2 * q]     = fmaf(m, f.x, a[2 * q]);
    a[2 * q + 1] = fmaf(m, f.y, a[2 * q + 1]);
  }
}

// unmasked accumulate
__device__ __forceinline__ void add8(float* a, uint4 u) {
  const __half2* hp = (const __half2*)&u;
#pragma unroll
  for (int q = 0; q < 4; ++q) {
    float2 f = __half22float2(hp[q]);
    a[2 * q]     += f.x;
    a[2 * q + 1] += f.y;
  }
}

// LDS-tile multisplit with 4-way sub-histograms (per-wave)
__global__ void k_part(const int* __restrict__ src, const int* __restrict__ dst,
                       int* __restrict__ gcur, unsigned* __restrict__ pairs,
                       int n_edges, int n_nodes, int chunk) {
  __shared__ int hist[NBUCK * 4];
  __shared__ int base[NBUCK * 4];
  int t = threadIdx.x;
  int g = t >> 6;
  int beg = blockIdx.x * chunk;
  int end = min(beg + chunk, n_edges);
  for (int tbeg = beg; tbeg < end; tbeg += TILE) {
    int cnt = min(TILE, end - tbeg);
    hist[t] = 0; hist[t + 256] = 0; hist[t + 512] = 0; hist[t + 768] = 0;
    __syncthreads();
    unsigned pk[EPT];
    int r[EPT], bk[EPT];
    bool v[EPT];
#pragma unroll
    for (int k = 0; k < EPT; ++k) {
      int li = k * 256 + t;
      v[k] = li < cnt;
      if (v[k]) {
        int i = tbeg + li;
        int s = src[i];
        int d = dst[i];
        bk[k] = bucket_of(d, n_nodes);
        unsigned nb0 = ((unsigned)bk[k] * (unsigned)n_nodes + 255u) >> 8;
        pk[k] = (((unsigned)d - nb0) << 18) | (unsigned)s;
        r[k] = atomicAdd(&hist[bk[k] * 4 + g], 1);
      }
    }
    __syncthreads();
    int h0 = hist[t * 4 + 0], h1 = hist[t * 4 + 1];
    int h2 = hist[t * 4 + 2], h3 = hist[t * 4 + 3];
    int tot = h0 + h1 + h2 + h3;
    int b0 = (tot > 0) ? atomicAdd(&gcur[t], tot) : 0;
    base[t * 4 + 0] = b0;
    base[t * 4 + 1] = b0 + h0;
    base[t * 4 + 2] = b0 + h0 + h1;
    base[t * 4 + 3] = b0 + h0 + h1 + h2;
    __syncthreads();
#pragma unroll
    for (int k = 0; k < EPT; ++k)
      if (v[k]) pairs[base[bk[k] * 4 + g] + r[k]] = pk[k];
    __syncthreads();
  }
}

// one block per bucket: LDS node-hist -> scan -> obeg/oend (into SPARSE idx);
// scatter packed (x[src]<<18|src) into the bucket's own region.
__global__ void k_bucket(const unsigned* __restrict__ pairs, const int* __restrict__ gcur,
                         const int* __restrict__ x, int* __restrict__ obeg,
                         int* __restrict__ oend, unsigned* __restrict__ idx,
                         int n_nodes, int cap) {
  __shared__ int lcnt[MAXN];
  __shared__ int lcur[MAXN];
  __shared__ int stmp[256];
  int b = blockIdx.x, t = threadIdx.x;
  int nb0 = (int)((((unsigned)b * (unsigned)n_nodes) + 255u) >> 8);
  int nb1 = (int)((((unsigned)(b + 1) * (unsigned)n_nodes) + 255u) >> 8);
  if (nb1 > n_nodes) nb1 = n_nodes;
  int nn = nb1 - nb0;
  int rbeg = b * cap;
  int rend = gcur[b];
  for (int i = t; i < nn; i += 256) lcnt[i] = 0;
  __syncthreads();
  for (int i = rbeg + t; i < rend; i += 256)
    atomicAdd(&lcnt[pairs[i] >> 18], 1);
  __syncthreads();
  int i0 = t * 4;
  int v0 = (i0 + 0 < nn) ? lcnt[i0 + 0] : 0;
  int v1 = (i0 + 1 < nn) ? lcnt[i0 + 1] : 0;
  int v2 = (i0 + 2 < nn) ? lcnt[i0 + 2] : 0;
  int v3 = (i0 + 3 < nn) ? lcnt[i0 + 3] : 0;
  stmp[t] = v0 + v1 + v2 + v3;
  __syncthreads();
  for (int off = 1; off < 256; off <<= 1) {
    int add = (t >= off) ? stmp[t - off] : 0;
    __syncthreads();
    stmp[t] += add;
    __syncthreads();
  }
  int run = rbeg + ((t == 0) ? 0 : stmp[t - 1]);
  if (i0 + 0 < nn) { lcur[i0 + 0] = run; obeg[nb0 + i0 + 0] = run; oend[nb0 + i0 + 0] = run + v0; run += v0; }
  if (i0 + 1 < nn) { lcur[i0 + 1] = run; obeg[nb0 + i0 + 1] = run; oend[nb0 + i0 + 1] = run + v1; run += v1; }
  if (i0 + 2 < nn) { lcur[i0 + 2] = run; obeg[nb0 + i0 + 2] = run; oend[nb0 + i0 + 2] = run + v2; run += v2; }
  if (i0 + 3 < nn) { lcur[i0 + 3] = run; obeg[nb0 + i0 + 3] = run; oend[nb0 + i0 + 3] = run + v3; run += v3; }
  __syncthreads();
  for (int i = rbeg + t; i < rend; i += 256) {
    unsigned e = pairs[i];
    int s = (int)(e & 0x3FFFFu);
    int pos = atomicAdd(&lcur[e >> 18], 1);
    idx[pos] = ((unsigned)x[s] << 18) | (unsigned)s;
  }
}

__global__ void k_transpose4(const float* __restrict__ a0, const float* __restrict__ a1,
                             const float* __restrict__ a2, const float* __restrict__ a3,
                             float* __restrict__ wt) {
  const float* s = (blockIdx.x == 0) ? a0 : (blockIdx.x == 1) ? a1 : (blockIdx.x == 2) ? a2 : a3;
  float* d = wt + blockIdx.x * 4096;
  for (int i = threadIdx.x; i < 4096; i += blockDim.x) {
    int r = i >> 6, c = i & 63;
    d[c * 64 + r] = s[i];
  }
}

// pack W2l,W2r into MFMA B-fragment order (same k-map as A: k=(l>>4)*8+j)
// + folds cursor init (block 0).
__global__ void k_packB(const float* __restrict__ W2l, const float* __restrict__ W2r,
                        __half* __restrict__ pB, int* __restrict__ gcur, int cap) {
  if (blockIdx.x == 0) gcur[threadIdx.x] = threadIdx.x * cap;
  int i = blockIdx.x * 256 + threadIdx.x;
  if (i >= 8192) return;
  int j = i & 7, l = (i >> 3) & 63, kt = (i >> 9) & 1, nt = (i >> 10) & 3, mat = i >> 12;
  int k = kt * 32 + (l >> 4) * 8 + j;
  int n = nt * 16 + (l & 15);
  const float* W = mat ? W2r : W2l;
  pB[i] = __float2half(W[n * 64 + k]);
}

__global__ void k_prep(const float* __restrict__ emb, const float* __restrict__ w1lT,
                       const float* __restrict__ w1rT, const float* __restrict__ b1,
                       __half* __restrict__ te, float* __restrict__ trb, int vocab) {
  __shared__ float se[NPB][64];
  int wid = threadIdx.x >> 6, lane = threadIdx.x & 63;
  int v = blockIdx.x * NPB + wid;
  if (v >= vocab) return;
  se[wid][lane] = emb[(size_t)v * 64 + lane];
  __syncwarp();
  float aL = 0.f, aR = b1[lane];
#pragma unroll 8
  for (int f = 0; f < 64; ++f) {
    float ev = se[wid][f];
    aL = fmaf(ev, w1lT[f * 64 + lane], aL);
    aR = fmaf(ev, w1rT[f * 64 + lane], aR);
  }
  te[(size_t)v * 64 + lane] = __float2half(aL);
  trb[(size_t)v * 64 + lane] = aR;
}

// gather + mean + trb + relu -> h1 (fp16); all chunk loads issued before acc
__global__ __launch_bounds__(64, 6) void
k_gather1(const unsigned* __restrict__ idx, const int* __restrict__ obeg,
          const int* __restrict__ oend, const __half* __restrict__ te,
          const float* __restrict__ trb, const int* __restrict__ x,
          __half* __restrict__ h1, int n_nodes) {
  int lane = threadIdx.x;
  int r8 = lane >> 3, s8 = (lane & 7) << 3;
  int node = blockIdx.x;
  if (node >= n_nodes) return;
  int xv = x[node];                    // hoisted (feeds trb much later)
  int beg = obeg[node], end = oend[node];
  float a[8];
#pragma unroll
  for (int q = 0; q < 8; ++q) a[q] = 0.f;
  for (int c = beg; c < end; c += 64) {
    int nit = min(end - c, 64);
    unsigned eidx = idx[c + min(lane, nit - 1)];
    int ngrp = (nit + 7) >> 3;
    int nfg = nit >> 3;
    uint4 u0, u1, u2, u3, u4, u5, u6, u7;
#define CLD1(J) if (J < ngrp) { \
      int vv = (int)(__shfl(eidx, min(J * 8 + r8, nit - 1)) >> 18); \
      u##J = *(const uint4*)(te + ((size_t)vv << 6) + s8); }
    CLD1(0) CLD1(1) CLD1(2) CLD1(3) CLD1(4) CLD1(5) CLD1(6) CLD1(7)
#undef CLD1
#define CACC1(J) if (J < nfg) add8(a, u##J); \
    else if (J < ngrp) acc8h(a, u##J, (J * 8 + r8 < nit) ? 1.f : 0.f);
    CACC1(0) CACC1(1) CACC1(2) CACC1(3) CACC1(4) CACC1(5) CACC1(6) CACC1(7)
#undef CACC1
  }
  // issue trb rows before the reduce so their latency hides under it
  float4 t0, t1;
  if (lane < 8) {
    const float* tp = trb + ((size_t)xv << 6) + s8;
    t0 = *(const float4*)tp;
    t1 = *(const float4*)(tp + 4);
  }
#pragma unroll
  for (int q = 0; q < 8; ++q) {
    a[q] += __shfl_xor(a[q], 8);
    a[q] += __shfl_xor(a[q], 16);
    a[q] += __shfl_xor(a[q], 32);
  }
  int deg = end - beg;
  float inv = (deg > 0) ? 1.f / (float)deg : 0.f;
  if (lane < 8) {
    __half hh[8];
    hh[0] = __float2half(fmaxf(fmaf(a[0], inv, t0.x), 0.f));
    hh[1] = __float2half(fmaxf(fmaf(a[1], inv, t0.y), 0.f));
    hh[2] = __float2half(fmaxf(fmaf(a[2], inv, t0.z), 0.f));
    hh[3] = __float2half(fmaxf(fmaf(a[3], inv, t0.w), 0.f));
    hh[4] = __float2half(fmaxf(fmaf(a[4], inv, t1.x), 0.f));
    hh[5] = __float2half(fmaxf(fmaf(a[5], inv, t1.y), 0.f));
    hh[6] = __float2half(fmaxf(fmaf(a[6], inv, t1.z), 0.f));
    hh[7] = __float2half(fmaxf(fmaf(a[7], inv, t1.w), 0.f));
    *(uint4*)(h1 + ((size_t)node << 6) + s8) = *(uint4*)hh;
  }
}

// MFMA mini-GEMM: [16 nodes x 64] @ {W2l^T, W2r^T} -> g1 (fp16), s1 (fp32, +b2)
__global__ __launch_bounds__(64) void
k_gemm(const __half* __restrict__ h1, const __half* __restrict__ pB,
       const float* __restrict__ b2, __half* __restrict__ g1,
       float* __restrict__ s1, int n_nodes) {
  int lane = threadIdx.x;
  int nbase = blockIdx.x * 16;
  int row = lane & 15, grp = lane >> 4;
  const half8 a0 = *(const half8*)(h1 + ((size_t)(nbase + row) << 6) + grp * 8);
  const half8 a1 = *(const half8*)(h1 + ((size_t)(nbase + row) << 6) + 32 + grp * 8);
#pragma unroll
  for (int t = 0; t < 8; ++t) {
    const half8 b0 = *(const half8*)(pB + (t * 2 + 0) * 512 + lane * 8);
    const half8 b1 = *(const half8*)(pB + (t * 2 + 1) * 512 + lane * 8);
    f32x4 acc = {0.f, 0.f, 0.f, 0.f};
    acc = __builtin_amdgcn_mfma_f32_16x16x32_f16(a0, b0, acc, 0, 0, 0);
    acc = __builtin_amdgcn_mfma_f32_16x16x32_f16(a1, b1, acc, 0, 0, 0);
    int out = (t & 3) * 16 + (lane & 15);
    if (t < 4) {
#pragma unroll
      for (int r = 0; r < 4; ++r) {
        int node = nbase + grp * 4 + r;
        if (node < n_nodes) g1[((size_t)node << 6) + out] = __float2half(acc[r]);
      }
    } else {
      float bias = b2[out];
#pragma unroll
      for (int r = 0; r < 4; ++r) {
        int node = nbase + grp * 4 + r;
        if (node < n_nodes) s1[((size_t)node << 6) + out] = acc[r] + bias;
      }
    }
  }
}

// conv2: gather g1 + mean + s1 + relu -> o = h2@Wout^T; RT-chain optimized
__global__ __launch_bounds__(64, 6) void
k_conv2(const unsigned* __restrict__ idx, const int* __restrict__ obeg,
        const int* __restrict__ oend, const __half* __restrict__ g1,
        const float* __restrict__ s1, const float* __restrict__ wout,
        float* __restrict__ o, int n_nodes) {
  __shared__ float sm[64];
  int lane = threadIdx.x;
  int r8 = lane >> 3, s8 = (lane & 7) << 3;
  int node = blockIdx.x;
  if (node >= n_nodes) return;
  float s1v = s1[((size_t)node << 6) + lane];   // hoisted off critical path
  float w0 = wout[lane], w1v = wout[64 + lane]; // hoisted
  int beg = obeg[node], end = oend[node];
  float a[8];
#pragma unroll
  for (int q = 0; q < 8; ++q) a[q] = 0.f;
  for (int c = beg; c < end; c += 64) {
    int nit = min(end - c, 64);
    unsigned eidx = idx[c + min(lane, nit - 1)];
    int ngrp = (nit + 7) >> 3;
    int nfg = nit >> 3;
    uint4 u0, u1, u2, u3, u4, u5, u6, u7;
#define CLD2(J) if (J < ngrp) { \
      int vv = (int)(__shfl(eidx, min(J * 8 + r8, nit - 1)) & 0x3FFFFu); \
      u##J = *(const uint4*)(g1 + ((size_t)vv << 6) + s8); }
    CLD2(0) CLD2(1) CLD2(2) CLD2(3) CLD2(4) CLD2(5) CLD2(6) CLD2(7)
#undef CLD2
#define CACC2(J) if (J < nfg) add8(a, u##J); \
    else if (J < ngrp) acc8h(a, u##J, (J * 8 + r8 < nit) ? 1.f : 0.f);
    CACC2(0) CACC2(1) CACC2(2) CACC2(3) CACC2(4) CACC2(5) CACC2(6) CACC2(7)
#undef CACC2
  }
#pragma unroll
  for (int q = 0; q < 8; ++q) {
    a[q] += __shfl_xor(a[q], 8);
    a[q] += __shfl_xor(a[q], 16);
    a[q] += __shfl_xor(a[q], 32);
  }
  int deg = end - beg;
  float inv = (deg > 0) ? 1.f / (float)deg : 0.f;
  if (lane < 8) {
#pragma unroll
    for (int q = 0; q < 8; ++q) sm[s8 + q] = a[q] * inv;
  }
  __syncthreads();
  float h2 = fmaxf(sm[lane] + s1v, 0.f);
  float p0 = h2 * w0;
  float p1 = h2 * w1v;
  for (int off = 32; off > 0; off >>= 1) {
    p0 += __shfl_down(p0, off);
    p1 += __shfl_down(p1, off);
  }
  if (lane == 0) {
    o[((size_t)node << 1) + 0] = p0;
    o[((size_t)node << 1) + 1] = p1;
  }
}

__global__ void k_goffs(const int* __restrict__ batch, int* __restrict__ goffs,
                        int n_nodes, int n_graphs) {
  int i = blockIdx.x * blockDim.x + threadIdx.x;
  if (i >= n_nodes) return;
  int b = batch[i];
  int bp = (i == 0) ? -1 : batch[i - 1];
  for (int g = bp + 1; g <= b; ++g) goffs[g] = i;
  if (i == n_nodes - 1)
    for (int g = b + 1; g <= n_graphs; ++g) goffs[g] = n_nodes;
}

__global__ void k_pool(const float2* __restrict__ o, const int* __restrict__ goffs,
                       const float* __restrict__ bout, float* __restrict__ out,
                       int n_graphs) {
  int wid = threadIdx.x >> 6, lane = threadIdx.x & 63;
  int g = blockIdx.x * NPB + wid;
  if (g >= n_graphs) return;
  int beg = goffs[g], end = goffs[g + 1];
  float a0 = 0.f, a1 = 0.f;
  for (int n = beg + lane; n < end; n += 64) {
    float2 v = o[n];
    a0 += v.x;
    a1 += v.y;
  }
  for (int off = 32; off > 0; off >>= 1) {
    a0 += __shfl_down(a0, off);
    a1 += __shfl_down(a1, off);
  }
  if (lane == 0) {
    int cnt = end - beg;
    float inv = (cnt > 0) ? 1.f / (float)cnt : 0.f;
    out[g * 2 + 0] = a0 * inv + bout[0];
    out[g * 2 + 1] = a1 * inv + bout[1];
  }
}

extern "C" void kernel_launch(void* const* d_in, const int* in_sizes, int n_in,
                              void* d_out, int out_size, void* d_ws, size_t ws_size,
                              hipStream_t stream) {
  const int* x = (const int*)d_in[0];
  const int* ei = (const int*)d_in[1];
  const int* batch = (const int*)d_in[2];
  const float* emb = (const float*)d_in[3];
  const float* W1l = (const float*)d_in[4];
  const float* b1 = (const float*)d_in[5];
  const float* W1r = (const float*)d_in[6];
  const float* W2l = (const float*)d_in[7];
  const float* b2 = (const float*)d_in[8];
  const float* W2r = (const float*)d_in[9];
  const float* Wout = (const float*)d_in[10];
  const float* bout = (const float*)d_in[11];
  float* out = (float*)d_out;

  int n_nodes = in_sizes[0];
  int n_edges = in_sizes[1] / 2;
  int vocab = in_sizes[3] / 64;
  int n_graphs = out_size / 2;
  const int* src = ei;
  const int* dst = ei + n_edges;

  int cap = n_edges / NBUCK + n_edges / (NBUCK * 8) + 1024;
  int ntiles = (n_nodes + 15) / 16;

  char* p = (char*)d_ws;
  auto alloc = [&](size_t bytes) -> void* {
    void* r = (void*)p;
    p += (bytes + 255) & ~(size_t)255;
    return r;
  };
  __half* te = (__half*)alloc((size_t)vocab * 64 * 2);
  float* trb = (float*)alloc((size_t)vocab * 64 * 4);
  float* wt = (float*)alloc(2 * 4096 * 4);
  __half* pB = (__half*)alloc(8192 * 2);
  int* obeg = (int*)alloc((size_t)n_nodes * 4);
  int* oend = (int*)alloc((size_t)n_nodes * 4);
  int* goffs = (int*)alloc((size_t)(n_graphs + 1) * 4);
  int* gcur = (int*)alloc(NBUCK * 4);
  unsigned* idx = (unsigned*)alloc((size_t)NBUCK * cap * 4);  // bucket-sparse
  __half* h1 = (__half*)alloc((size_t)(ntiles * 16) * 64 * 2);
  size_t pairs_bytes = (size_t)NBUCK * cap * 4;
  size_t g1_bytes = (size_t)n_nodes * 64 * 2;
  unsigned* pairs = (unsigned*)alloc(pairs_bytes > g1_bytes ? pairs_bytes : g1_bytes);
  float* s1 = (float*)alloc((size_t)n_nodes * 64 * 4);
  float* o = (float*)alloc((size_t)n_nodes * 2 * 4);
  __half* g1 = (__half*)pairs;  // pairs dead before k_gemm writes g1

  k_packB<<<32, 256, 0, stream>>>(W2l, W2r, pB, gcur, cap);  // + cursor init
  k_transpose4<<<2, 256, 0, stream>>>(W1l, W1r, W1l, W1l, wt);
  k_prep<<<(vocab + NPB - 1) / NPB, 64 * NPB, 0, stream>>>(emb, wt, wt + 4096, b1, te, trb, vocab);

  int part_blocks = 512;
  int chunk = (n_edges + part_blocks - 1) / part_blocks;
  k_part<<<part_blocks, 256, 0, stream>>>(src, dst, gcur, pairs, n_edges, n_nodes, chunk);
  k_bucket<<<NBUCK, 256, 0, stream>>>(pairs, gcur, x, obeg, oend, idx, n_nodes, cap);

  k_goffs<<<(n_nodes + 255) / 256, 256, 0, stream>>>(batch, goffs, n_nodes, n_graphs);

  k_gather1<<<n_nodes, 64, 0, stream>>>(idx, obeg, oend, te, trb, x, h1, n_nodes);
  k_gemm<<<ntiles, 64, 0, stream>>>(h1, pB, b2, g1, s1, n_nodes);
  k_conv2<<<n_nodes, 64, 0, stream>>>(idx, obeg, oend, g1, s1, Wout, o, n_nodes);
  k_pool<<<(n_graphs + NPB - 1) / NPB, 64 * NPB, 0, stream>>>((const float2*)o, goffs, bout, out, n_graphs);
}